// Round 2
// baseline (262.711 us; speedup 1.0000x reference)
//
#include <hip/hip_runtime.h>
#include <math.h>

// Fused 3-layer MLP: h1 = relu(x@W1^T+b1) [B,3]; h2 = relu(h1@W2^T+b2) [B,2];
// out = sigmoid(h2@W3^T+b3) [B].  All fp32.  Memory-bound: 32 B/row traffic
// (8 B read + 24 B write), 256 MiB total at B=8.39M -> ~41 us floor @6.3 TB/s.
//
// R1/R2 (prev session): LDS-stage outputs, coalesced float4 drain.
// R3: nt->plain stores, RPB 512, vectorized LDS writes -> ALL NULL (dur_us
//     unchanged). Post-mortem: kernel ~= 120 us (260 - 123 fill - ~15 resets),
//     i.e. ~2.2 TB/s despite perfect coalescing & 0 bank conflicts ->
//     NOT store-path/bank/wave-count bound. The shared structure of R2/R3 is
//     16384 short-lived blocks each paying a serial {weight-load chain ->
//     x-load -> compute -> barrier -> drain} latency chain: latency-bound.
// R4 (this round): persistent grid-stride kernel.
//   - 2048 blocks, ~6 resident/CU (24 KiB LDS), each handles ~8 chunks.
//   - Weights loaded ONCE per block (8x fewer weight-load chains).
//   - Double-buffered LDS + next-chunk x prefetch issued BEFORE the barrier:
//     global-load latency of chunk i+1 hides under the drain of chunk i.
//   - One barrier per chunk is sufficient: all drain-i reads of buf A complete
//     before any thread passes barrier i+1, which precedes any i+2 write to A.

#define RPB 512   // rows per chunk (256 threads x 2 rows)
#define NBLK 2048 // persistent grid; 16384 chunks / 2048 = 8 per block

typedef float v4f __attribute__((ext_vector_type(4)));
typedef float v2f __attribute__((ext_vector_type(2)));

__global__ __launch_bounds__(256) void mlp321_kernel(
    const float* __restrict__ x,
    const float* __restrict__ W1, const float* __restrict__ b1,
    const float* __restrict__ W2, const float* __restrict__ b2,
    const float* __restrict__ W3, const float* __restrict__ b3,
    float* __restrict__ out_p, float* __restrict__ h1_p, float* __restrict__ h2_p,
    int nrows)
{
    __shared__ __align__(16) float s_h1[2][RPB * 3];  // 2 x 6 KB
    __shared__ __align__(16) float s_h2[2][RPB * 2];  // 2 x 4 KB
    __shared__ __align__(16) float s_out[2][RPB];     // 2 x 2 KB

    const int tid = threadIdx.x;

    // Weights: tiny, uniform -> scalar loads, ONCE per persistent block.
    float w1[6], w2[6], w3v[2], bb1[3], bb2[2], bb3;
#pragma unroll
    for (int i = 0; i < 6; ++i) w1[i] = W1[i];
#pragma unroll
    for (int i = 0; i < 3; ++i) bb1[i] = b1[i];
#pragma unroll
    for (int i = 0; i < 6; ++i) w2[i] = W2[i];
#pragma unroll
    for (int i = 0; i < 2; ++i) bb2[i] = b2[i];
    w3v[0] = W3[0]; w3v[1] = W3[1];
    bb3 = b3[0];

    const int nfull = nrows / RPB;   // full chunks
    const int gsz = gridDim.x;
    const v4f* xv = reinterpret_cast<const v4f*>(x);

    int c = blockIdx.x;
    int buf = 0;
    v4f xa = {0.f, 0.f, 0.f, 0.f};
    if (c < nfull) xa = xv[(size_t)c * 256 + tid];  // chunk c: 256 v4f

    while (c < nfull) {
        // ---- compute 2 rows from registers, write LDS buf ----
        const float xr[2][2] = {{xa.x, xa.y}, {xa.z, xa.w}};
        float h1v[2][3], h2v[2][2], ov[2];
#pragma unroll
        for (int r = 0; r < 2; ++r) {
            const float x0 = xr[r][0], x1 = xr[r][1];
#pragma unroll
            for (int j = 0; j < 3; ++j) {
                float v = fmaf(x0, w1[j * 2 + 0], fmaf(x1, w1[j * 2 + 1], bb1[j]));
                h1v[r][j] = v > 0.f ? v : 0.f;
            }
#pragma unroll
            for (int k = 0; k < 2; ++k) {
                float v = bb2[k];
#pragma unroll
                for (int j = 0; j < 3; ++j) v = fmaf(h1v[r][j], w2[k * 3 + j], v);
                h2v[r][k] = v > 0.f ? v : 0.f;
            }
            const float z = fmaf(h2v[r][0], w3v[0], fmaf(h2v[r][1], w3v[1], bb3));
            ov[r] = __builtin_amdgcn_rcpf(1.f + __expf(-z));
        }
        // Vectorized LDS writes (conflict-free per 16-lane phase).
        v2f* h1w = reinterpret_cast<v2f*>(&s_h1[buf][6 * tid]);
        h1w[0] = (v2f){h1v[0][0], h1v[0][1]};
        h1w[1] = (v2f){h1v[0][2], h1v[1][0]};
        h1w[2] = (v2f){h1v[1][1], h1v[1][2]};
        *reinterpret_cast<v4f*>(&s_h2[buf][4 * tid]) =
            (v4f){h2v[0][0], h2v[0][1], h2v[1][0], h2v[1][1]};
        *reinterpret_cast<v2f*>(&s_out[buf][2 * tid]) = (v2f){ov[0], ov[1]};

        // ---- prefetch next chunk's x BEFORE the barrier ----
        const int cn = c + gsz;
        v4f xn = {0.f, 0.f, 0.f, 0.f};
        if (cn < nfull) xn = xv[(size_t)cn * 256 + tid];

        __syncthreads();

        // ---- drain chunk c: fully coalesced float4 stores ----
        const size_t base = (size_t)c * RPB;
        const v4f* so = reinterpret_cast<const v4f*>(s_out[buf]);
        const v4f* s1 = reinterpret_cast<const v4f*>(s_h1[buf]);
        const v4f* s2 = reinterpret_cast<const v4f*>(s_h2[buf]);
        v4f* po = reinterpret_cast<v4f*>(out_p + base);       // 128 v4f
        v4f* p1 = reinterpret_cast<v4f*>(h1_p + base * 3);    // 384 v4f
        v4f* p2 = reinterpret_cast<v4f*>(h2_p + base * 2);    // 256 v4f
        p1[tid] = s1[tid];
        p2[tid] = s2[tid];
        if (tid < 128) {
            p1[256 + tid] = s1[256 + tid];
        } else {
            po[tid - 128] = so[tid - 128];
        }

        xa = xn;
        c = cn;
        buf ^= 1;
    }

    // ---- tail rows (nrows % RPB): direct scalar path, owning block only ----
    const int tail = nrows - nfull * RPB;
    if (tail && (int)blockIdx.x == (gsz ? (nfull % gsz) : 0)) {
        for (int r = tid; r < tail; r += 256) {
            const size_t row = (size_t)nfull * RPB + r;
            const float x0 = x[row * 2 + 0], x1 = x[row * 2 + 1];
            float h1v[3];
#pragma unroll
            for (int j = 0; j < 3; ++j) {
                float v = fmaf(x0, w1[j * 2 + 0], fmaf(x1, w1[j * 2 + 1], bb1[j]));
                h1v[j] = v > 0.f ? v : 0.f;
                h1_p[row * 3 + j] = h1v[j];
            }
            float h2v[2];
#pragma unroll
            for (int k = 0; k < 2; ++k) {
                float v = bb2[k];
#pragma unroll
                for (int j = 0; j < 3; ++j) v = fmaf(h1v[j], w2[k * 3 + j], v);
                h2v[k] = v > 0.f ? v : 0.f;
                h2_p[row * 2 + k] = h2v[k];
            }
            const float z = fmaf(h2v[0], w3v[0], fmaf(h2v[1], w3v[1], bb3));
            out_p[row] = __builtin_amdgcn_rcpf(1.f + __expf(-z));
        }
    }
}

extern "C" void kernel_launch(void* const* d_in, const int* in_sizes, int n_in,
                              void* d_out, int out_size, void* d_ws, size_t ws_size,
                              hipStream_t stream) {
    const float* x  = (const float*)d_in[0];
    const float* W1 = (const float*)d_in[1];
    const float* b1 = (const float*)d_in[2];
    const float* W2 = (const float*)d_in[3];
    const float* b2 = (const float*)d_in[4];
    const float* W3 = (const float*)d_in[5];
    const float* b3 = (const float*)d_in[6];

    const int B = in_sizes[0] / 2;  // x is [B, 2]
    float* out_p = (float*)d_out;          // [B]
    float* h1_p  = out_p + (size_t)B;      // [B,3]
    float* h2_p  = h1_p + (size_t)B * 3;   // [B,2]

    const int nfull = B / RPB;
    int blocks = nfull < NBLK ? nfull : NBLK;
    if (blocks < 1) blocks = 1;
    mlp321_kernel<<<blocks, 256, 0, stream>>>(x, W1, b1, W2, b2, W3, b3,
                                              out_p, h1_p, h2_p, B);
}